// Round 1
// baseline (810.848 us; speedup 1.0000x reference)
//
#include <hip/hip_runtime.h>

#define NN 50000   // nodes
#define NE 800000  // edges
#define DD 128     // feature dim

// ---------------------------------------------------------------------------
// Kernel 1: edge scatter. One 64-lane wave per edge.
// Each lane loads float2 of feature[src] (512B/edge coalesced) and does two
// f32 atomic adds into summed[dst]. Lane 0 increments in-degree count.
// ---------------------------------------------------------------------------
__global__ __launch_bounds__(256) void k_scatter(
    const float* __restrict__ feat, const int* __restrict__ src,
    const int* __restrict__ dst, float* __restrict__ summed,
    float* __restrict__ cnt) {
  int wave = threadIdx.x >> 6;
  int lane = threadIdx.x & 63;
  int e = blockIdx.x * 4 + wave;
  if (e >= NE) return;
  int s = src[e];
  int d = dst[e];
  float2 v = ((const float2*)(feat + (long long)s * DD))[lane];
  float* op = summed + (long long)d * DD + lane * 2;
  atomicAdd(op, v.x);
  atomicAdd(op + 1, v.y);
  if (lane == 0) atomicAdd(cnt + d, 1.0f);
}

// ---------------------------------------------------------------------------
// Kernel 2: fused mean + GEMM(W^T) + bias + ReLU, in-place on io (= summed).
// Block = 256 threads, 32 rows per block. K split into two halves of 64 so
// static LDS stays under 64KB (Ws half 33.3KB + hs 9.2KB = 42.5KB).
//   Ws[c][kk] (pad 65): read Ws[tc+32j][kk] -> bank = tc -> conflict-free.
//   hs[kk][r] (pad 36): transposed; staging writes map r=lane -> conflict-free;
//                       k-loop read is one broadcast ds_read_b128.
// Each thread computes a 4x4 tile: rows 4*tr..4*tr+3, cols tc+{0,32,64,96}.
// ---------------------------------------------------------------------------
__global__ __launch_bounds__(256) void k_mean_gemm(
    float* __restrict__ io, const float* __restrict__ cnt,
    const float* __restrict__ W, const float* __restrict__ bias) {
  __shared__ float Ws[DD][65];
  __shared__ __attribute__((aligned(16))) float hs[64][36];
  int tid = threadIdx.x;
  int row0 = blockIdx.x * 32;
  int tc = tid & 31;
  int tr = tid >> 5;

  float acc[4][4] = {};

  for (int p = 0; p < 2; ++p) {
    if (p) __syncthreads();
    // stage W half: 128 cols x 64 k = 2048 float4, 8 per thread
    for (int i = 0; i < 8; ++i) {
      int fidx = tid + (i << 8);
      int c = fidx >> 4;        // 0..127
      int kq = fidx & 15;       // 0..15 (float4 within the half)
      float4 w = ((const float4*)W)[c * 32 + p * 16 + kq];
      int kk = kq << 2;
      Ws[c][kk + 0] = w.x;
      Ws[c][kk + 1] = w.y;
      Ws[c][kk + 2] = w.z;
      Ws[c][kk + 3] = w.w;
    }
    // stage h half: 32 rows x 64 k = 512 float4, 2 per thread
    // r = lane -> LDS write bank = r -> conflict-free (global read is 16B
    // granular gather; L1/L2 absorb, staging volume is tiny)
    for (int i = 0; i < 2; ++i) {
      int fidx = tid + (i << 8);
      int r = fidx & 31;
      int kq = fidx >> 5;       // 0..15
      int grow = row0 + r;
      float4 v = make_float4(0.f, 0.f, 0.f, 0.f);
      if (grow < NN) {
        v = ((const float4*)io)[(long long)grow * 32 + p * 16 + kq];
        float c = cnt[grow];
        float inv = 1.0f / fmaxf(c, 1.0f);
        v.x *= inv; v.y *= inv; v.z *= inv; v.w *= inv;
      }
      int kk = kq << 2;
      hs[kk + 0][r] = v.x;
      hs[kk + 1][r] = v.y;
      hs[kk + 2][r] = v.z;
      hs[kk + 3][r] = v.w;
    }
    __syncthreads();

    for (int kk = 0; kk < 64; ++kk) {
      float4 h4 = *(const float4*)&hs[kk][tr << 2];
      float w0 = Ws[tc][kk];
      float w1 = Ws[tc + 32][kk];
      float w2 = Ws[tc + 64][kk];
      float w3 = Ws[tc + 96][kk];
      acc[0][0] += h4.x * w0; acc[0][1] += h4.x * w1;
      acc[0][2] += h4.x * w2; acc[0][3] += h4.x * w3;
      acc[1][0] += h4.y * w0; acc[1][1] += h4.y * w1;
      acc[1][2] += h4.y * w2; acc[1][3] += h4.y * w3;
      acc[2][0] += h4.z * w0; acc[2][1] += h4.z * w1;
      acc[2][2] += h4.z * w2; acc[2][3] += h4.z * w3;
      acc[3][0] += h4.w * w0; acc[3][1] += h4.w * w1;
      acc[3][2] += h4.w * w2; acc[3][3] += h4.w * w3;
    }
  }

  float b0 = bias[tc];
  float b1 = bias[tc + 32];
  float b2 = bias[tc + 64];
  float b3 = bias[tc + 96];
  for (int i = 0; i < 4; ++i) {
    int row = row0 + (tr << 2) + i;
    if (row < NN) {
      float* orow = io + (long long)row * DD;
      orow[tc]      = fmaxf(acc[i][0] + b0, 0.f);
      orow[tc + 32] = fmaxf(acc[i][1] + b1, 0.f);
      orow[tc + 64] = fmaxf(acc[i][2] + b2, 0.f);
      orow[tc + 96] = fmaxf(acc[i][3] + b3, 0.f);
    }
  }
}

extern "C" void kernel_launch(void* const* d_in, const int* in_sizes, int n_in,
                              void* d_out, int out_size, void* d_ws, size_t ws_size,
                              hipStream_t stream) {
  const float* feature = (const float*)d_in[0];
  const int*   src     = (const int*)d_in[1];
  const int*   dst     = (const int*)d_in[2];
  const float* W       = (const float*)d_in[3];
  const float* bias    = (const float*)d_in[4];
  float* out = (float*)d_out;
  float* cnt = (float*)d_ws;  // 50000 floats = 200KB

  // zero the sum accumulator (d_out doubles as it) and the degree counts
  hipMemsetAsync(d_out, 0, (size_t)NN * DD * sizeof(float), stream);
  hipMemsetAsync(cnt, 0, (size_t)NN * sizeof(float), stream);

  // scatter: 4 edges per block (one per wave)
  int nblk_scatter = (NE + 3) / 4;
  hipLaunchKernelGGL(k_scatter, dim3(nblk_scatter), dim3(256), 0, stream,
                     feature, src, dst, out, cnt);

  // fused mean + GEMM + bias + relu (in-place on d_out)
  int nblk_gemm = (NN + 31) / 32;
  hipLaunchKernelGGL(k_mean_gemm, dim3(nblk_gemm), dim3(256), 0, stream,
                     out, cnt, W, bias);
}

// Round 2
// 261.747 us; speedup vs baseline: 3.0978x; 3.0978x over previous
//
#include <hip/hip_runtime.h>

#define NN 50000   // nodes
#define NE 800000  // edges
#define DD 128     // feature dim
#define NPAD 50176 // 196 * 256 (padded node count for scan kernels)

// ---------------------------------------------------------------------------
// ws layout (ints): cnt[NPAD] | pos[NPAD] | bsum[256] | bsumx[256] | csr[NE]
// ---------------------------------------------------------------------------

// 1) in-degree histogram: 800K int atomics over 50K counters (low contention)
__global__ __launch_bounds__(256) void k_hist(const int* __restrict__ dst,
                                              int* __restrict__ cnt) {
  int e = blockIdx.x * 256 + threadIdx.x;
  if (e < NE) atomicAdd(&cnt[dst[e]], 1);
}

// 2a) per-block partial sums of cnt
__global__ __launch_bounds__(256) void k_reduce(const int* __restrict__ cnt,
                                                int* __restrict__ bsum) {
  __shared__ int sh[256];
  int t = threadIdx.x;
  sh[t] = cnt[blockIdx.x * 256 + t];
  __syncthreads();
  for (int o = 128; o > 0; o >>= 1) {
    if (t < o) sh[t] += sh[t + o];
    __syncthreads();
  }
  if (t == 0) bsum[blockIdx.x] = sh[0];
}

// 2b) exclusive scan of the 196 block sums (single block)
__global__ __launch_bounds__(256) void k_scan_bsum(const int* __restrict__ bsum,
                                                   int* __restrict__ bsumx) {
  __shared__ int sh[256];
  int t = threadIdx.x;
  int v = (t < 196) ? bsum[t] : 0;
  sh[t] = v;
  __syncthreads();
  for (int o = 1; o < 256; o <<= 1) {
    int x = (t >= o) ? sh[t - o] : 0;
    __syncthreads();
    sh[t] += x;
    __syncthreads();
  }
  bsumx[t] = sh[t] - v;  // exclusive
}

// 2c) block-level exclusive scan + block base -> pos (CSR offsets)
__global__ __launch_bounds__(256) void k_scan_block(const int* __restrict__ cnt,
                                                    const int* __restrict__ bsumx,
                                                    int* __restrict__ pos) {
  __shared__ int sh[256];
  int t = threadIdx.x;
  int g = blockIdx.x * 256 + t;
  int v = cnt[g];
  sh[t] = v;
  __syncthreads();
  for (int o = 1; o < 256; o <<= 1) {
    int x = (t >= o) ? sh[t - o] : 0;
    __syncthreads();
    sh[t] += x;
    __syncthreads();
  }
  pos[g] = bsumx[blockIdx.x] + sh[t] - v;
}

// 3) fill CSR: csr[pos[dst]++] = src  (800K int atomics)
//    afterwards pos[n] == end offset of node n
__global__ __launch_bounds__(256) void k_fill(const int* __restrict__ src,
                                              const int* __restrict__ dst,
                                              int* __restrict__ pos,
                                              int* __restrict__ csr) {
  int e = blockIdx.x * 256 + threadIdx.x;
  if (e < NE) {
    int d = dst[e];
    int p = atomicAdd(&pos[d], 1);
    csr[p] = src[e];
  }
}

// 4) gather: one 64-lane wave per node; lane owns 2 columns (float2).
//    feature (25.6MB) is L2/L3-resident -> reads are cache hits; no atomics.
__global__ __launch_bounds__(256) void k_gather(const float* __restrict__ feat,
                                                const int* __restrict__ csr,
                                                const int* __restrict__ pos,
                                                const int* __restrict__ cnt,
                                                float* __restrict__ sum) {
  int n = blockIdx.x * 4 + (threadIdx.x >> 6);  // 12500*4 == 50000 exactly
  int lane = threadIdx.x & 63;
  int end = pos[n];
  int c = cnt[n];
  float ax = 0.f, ay = 0.f;
  for (int base = end - c; base < end; base += 64) {
    int m = end - base;
    if (m > 64) m = 64;
    int s = (base + lane < end) ? csr[base + lane] : 0;
    int j = 0;
    for (; j + 3 < m; j += 4) {  // 4 loads in flight per iter
      int s0 = __shfl(s, j), s1 = __shfl(s, j + 1);
      int s2 = __shfl(s, j + 2), s3 = __shfl(s, j + 3);
      float2 v0 = ((const float2*)(feat + (long long)s0 * DD))[lane];
      float2 v1 = ((const float2*)(feat + (long long)s1 * DD))[lane];
      float2 v2 = ((const float2*)(feat + (long long)s2 * DD))[lane];
      float2 v3 = ((const float2*)(feat + (long long)s3 * DD))[lane];
      ax += (v0.x + v1.x) + (v2.x + v3.x);
      ay += (v0.y + v1.y) + (v2.y + v3.y);
    }
    for (; j < m; ++j) {
      int sj = __shfl(s, j);
      float2 v = ((const float2*)(feat + (long long)sj * DD))[lane];
      ax += v.x;
      ay += v.y;
    }
  }
  float2 o;
  o.x = ax;
  o.y = ay;
  ((float2*)(sum + (long long)n * DD))[lane] = o;
}

// Fallback scatter (only if ws too small for CSR): f32 atomics, int cnt
__global__ __launch_bounds__(256) void k_scatter(const float* __restrict__ feat,
                                                 const int* __restrict__ src,
                                                 const int* __restrict__ dst,
                                                 float* __restrict__ summed,
                                                 int* __restrict__ cnt) {
  int wave = threadIdx.x >> 6;
  int lane = threadIdx.x & 63;
  int e = blockIdx.x * 4 + wave;
  if (e >= NE) return;
  int s = src[e];
  int d = dst[e];
  float2 v = ((const float2*)(feat + (long long)s * DD))[lane];
  float* op = summed + (long long)d * DD + lane * 2;
  atomicAdd(op, v.x);
  atomicAdd(op + 1, v.y);
  if (lane == 0) atomicAdd(&cnt[d], 1);
}

// ---------------------------------------------------------------------------
// 5) fused mean + GEMM(W^T) + bias + ReLU, in-place on io (= summed).
// 64 rows/block, 256 threads, per-thread tile 8 rows x 4 cols.
// Per kk: 3 ds_read_b128 (h0,h1,w4) feed 32 FMAs -> LDS demand ~= FMA demand.
// Wt is k-major with per-kk XOR swizzle (4-col granule) so staging writes
// spread across banks and reads stay b128 conflict-free.
// ---------------------------------------------------------------------------
__global__ __launch_bounds__(256) void k_gemm(float* __restrict__ io,
                                              const int* __restrict__ cnt,
                                              const float* __restrict__ W,
                                              const float* __restrict__ bias) {
  __shared__ float Wt[64][132];  // [kk][col^swz], stride 528B (16B aligned)
  __shared__ __attribute__((aligned(16))) float hs[64][72];  // [kk][row]
  int tid = threadIdx.x;
  int row0 = blockIdx.x * 64;
  int tc = tid & 31;  // cols 4*tc .. 4*tc+3
  int tr = tid >> 5;  // rows 8*tr .. 8*tr+7

  float acc[8][4] = {};

  for (int p = 0; p < 2; ++p) {
    if (p) __syncthreads();
    // stage Wt: W[c][p*64+kk] -> Wt[kk][c ^ ((kk&31)<<2)]
    for (int i = 0; i < 8; ++i) {
      int fidx = tid + (i << 8);
      int c = fidx >> 4;   // 0..127
      int kq = fidx & 15;  // float4 index within the 64-k half
      float4 w = ((const float4*)W)[c * 32 + p * 16 + kq];
      int kk = kq << 2;
      Wt[kk + 0][c ^ (((kk + 0) & 31) << 2)] = w.x;
      Wt[kk + 1][c ^ (((kk + 1) & 31) << 2)] = w.y;
      Wt[kk + 2][c ^ (((kk + 2) & 31) << 2)] = w.z;
      Wt[kk + 3][c ^ (((kk + 3) & 31) << 2)] = w.w;
    }
    // stage hs: 64 rows x 64 kk, mean applied here
    for (int i = 0; i < 4; ++i) {
      int fidx = tid + (i << 8);
      int r = fidx & 63;
      int kq = fidx >> 6;  // 0..15
      int grow = row0 + r;
      float4 v = make_float4(0.f, 0.f, 0.f, 0.f);
      if (grow < NN) {
        v = ((const float4*)io)[(long long)grow * 32 + p * 16 + kq];
        float inv = 1.0f / fmaxf((float)cnt[grow], 1.0f);
        v.x *= inv; v.y *= inv; v.z *= inv; v.w *= inv;
      }
      int kk = kq << 2;
      hs[kk + 0][r] = v.x;
      hs[kk + 1][r] = v.y;
      hs[kk + 2][r] = v.z;
      hs[kk + 3][r] = v.w;
    }
    __syncthreads();

#pragma unroll 4
    for (int kk = 0; kk < 64; ++kk) {
      float4 w4 = *(const float4*)&Wt[kk][(tc << 2) ^ ((kk & 31) << 2)];
      float4 h0 = *(const float4*)&hs[kk][tr << 3];
      float4 h1 = *(const float4*)&hs[kk][(tr << 3) + 4];
      acc[0][0] += h0.x * w4.x; acc[0][1] += h0.x * w4.y; acc[0][2] += h0.x * w4.z; acc[0][3] += h0.x * w4.w;
      acc[1][0] += h0.y * w4.x; acc[1][1] += h0.y * w4.y; acc[1][2] += h0.y * w4.z; acc[1][3] += h0.y * w4.w;
      acc[2][0] += h0.z * w4.x; acc[2][1] += h0.z * w4.y; acc[2][2] += h0.z * w4.z; acc[2][3] += h0.z * w4.w;
      acc[3][0] += h0.w * w4.x; acc[3][1] += h0.w * w4.y; acc[3][2] += h0.w * w4.z; acc[3][3] += h0.w * w4.w;
      acc[4][0] += h1.x * w4.x; acc[4][1] += h1.x * w4.y; acc[4][2] += h1.x * w4.z; acc[4][3] += h1.x * w4.w;
      acc[5][0] += h1.y * w4.x; acc[5][1] += h1.y * w4.y; acc[5][2] += h1.y * w4.z; acc[5][3] += h1.y * w4.w;
      acc[6][0] += h1.z * w4.x; acc[6][1] += h1.z * w4.y; acc[6][2] += h1.z * w4.z; acc[6][3] += h1.z * w4.w;
      acc[7][0] += h1.w * w4.x; acc[7][1] += h1.w * w4.y; acc[7][2] += h1.w * w4.z; acc[7][3] += h1.w * w4.w;
    }
  }

  float4 b4 = ((const float4*)bias)[tc];
#pragma unroll
  for (int r = 0; r < 8; ++r) {
    int row = row0 + (tr << 3) + r;
    if (row < NN) {
      float4 o;
      o.x = fmaxf(acc[r][0] + b4.x, 0.f);
      o.y = fmaxf(acc[r][1] + b4.y, 0.f);
      o.z = fmaxf(acc[r][2] + b4.z, 0.f);
      o.w = fmaxf(acc[r][3] + b4.w, 0.f);
      ((float4*)(io + (long long)row * DD))[tc] = o;
    }
  }
}

extern "C" void kernel_launch(void* const* d_in, const int* in_sizes, int n_in,
                              void* d_out, int out_size, void* d_ws, size_t ws_size,
                              hipStream_t stream) {
  const float* feature = (const float*)d_in[0];
  const int*   src     = (const int*)d_in[1];
  const int*   dst     = (const int*)d_in[2];
  const float* W       = (const float*)d_in[3];
  const float* bias    = (const float*)d_in[4];
  float* out = (float*)d_out;
  int* cnt = (int*)d_ws;

  size_t need = (size_t)(2 * NPAD + 512 + NE) * sizeof(int);  // ~3.6 MB
  int nblk_e = (NE + 255) / 256;   // 3125
  int nblk_gemm = (NN + 63) / 64;  // 782

  if (ws_size >= need) {
    int* pos   = cnt + NPAD;
    int* bsum  = pos + NPAD;
    int* bsumx = bsum + 256;
    int* csr   = bsumx + 256;
    hipMemsetAsync(cnt, 0, NPAD * sizeof(int), stream);
    hipLaunchKernelGGL(k_hist, dim3(nblk_e), dim3(256), 0, stream, dst, cnt);
    hipLaunchKernelGGL(k_reduce, dim3(196), dim3(256), 0, stream, cnt, bsum);
    hipLaunchKernelGGL(k_scan_bsum, dim3(1), dim3(256), 0, stream, bsum, bsumx);
    hipLaunchKernelGGL(k_scan_block, dim3(196), dim3(256), 0, stream, cnt, bsumx, pos);
    hipLaunchKernelGGL(k_fill, dim3(nblk_e), dim3(256), 0, stream, src, dst, pos, csr);
    hipLaunchKernelGGL(k_gather, dim3(NN / 4), dim3(256), 0, stream,
                       feature, csr, pos, cnt, out);
    hipLaunchKernelGGL(k_gemm, dim3(nblk_gemm), dim3(256), 0, stream,
                       out, cnt, W, bias);
  } else {
    // fallback: atomic scatter (ws only needs 200KB for cnt)
    hipMemsetAsync(out, 0, (size_t)NN * DD * sizeof(float), stream);
    hipMemsetAsync(cnt, 0, NN * sizeof(int), stream);
    hipLaunchKernelGGL(k_scatter, dim3((NE + 3) / 4), dim3(256), 0, stream,
                       feature, src, dst, out, cnt);
    hipLaunchKernelGGL(k_gemm, dim3(nblk_gemm), dim3(256), 0, stream,
                       out, cnt, W, bias);
  }
}